// Round 9
// baseline (480.567 us; speedup 1.0000x reference)
//
#include <hip/hip_runtime.h>
#include <math.h>

#define N_NODES 50000
#define N_PAD 50048          // multiple of 64 above 50000
#define N_EDGES 800000
#define DIM 256
#define N_GRAPHS 128
#define NSL 8                // dim slices; 3.2MB/slice table fits one XCD's 4MB L2

using f32x4 = __attribute__((ext_vector_type(4))) float;
using s16x8 = __attribute__((ext_vector_type(8))) short;

// ---------------- bf16 helpers ----------------
__device__ __forceinline__ ushort bf16_hi(float f) {
  unsigned u = __float_as_uint(f);
  return (ushort)((u + 0x7FFFu + ((u >> 16) & 1u)) >> 16);
}
__device__ __forceinline__ float bf16_up(ushort h) {
  return __uint_as_float(((unsigned)h) << 16);
}
__device__ __forceinline__ void bf16_split(float f, ushort& hh, ushort& ll) {
  hh = bf16_hi(f);
  float d = f - bf16_up(hh);
  ll = bf16_hi(d);
}

// ---------------- CSR build (atomic count only) ----------------
__global__ __launch_bounds__(256) void count_kernel(
    const int* __restrict__ dst, int* __restrict__ counts,
    int* __restrict__ p_local) {
  int e = blockIdx.x * 256 + threadIdx.x;
  if (e < N_EDGES) p_local[e] = atomicAdd(&counts[dst[e]], 1);
}

#define SCAN_CHUNK 1024
#define SCAN_BLOCKS ((N_NODES + SCAN_CHUNK - 1) / SCAN_CHUNK)

__global__ __launch_bounds__(256) void scan_phaseA(
    const int* __restrict__ counts, int* __restrict__ blockSums) {
  __shared__ int sdata[256];
  int b = blockIdx.x, t = threadIdx.x;
  int base = b * SCAN_CHUNK + t * 4;
  int s = 0;
#pragma unroll
  for (int i = 0; i < 4; ++i) {
    int idx = base + i;
    if (idx < N_NODES) s += counts[idx];
  }
  sdata[t] = s;
  __syncthreads();
  for (int off = 128; off > 0; off >>= 1) {
    if (t < off) sdata[t] += sdata[t + off];
    __syncthreads();
  }
  if (t == 0) blockSums[b] = sdata[0];
}

__global__ void scan_phaseB(int* __restrict__ blockSums, int* __restrict__ rs) {
  if (threadIdx.x == 0 && blockIdx.x == 0) {
    int acc = 0;
    for (int i = 0; i < SCAN_BLOCKS; ++i) {
      int v = blockSums[i];
      blockSums[i] = acc;
      acc += v;
    }
    rs[N_NODES] = acc;
  }
}

__global__ __launch_bounds__(256) void scan_phaseC(
    const int* __restrict__ counts, const int* __restrict__ blockSums,
    int* __restrict__ rs) {
  __shared__ int sdata[256];
  int b = blockIdx.x, t = threadIdx.x;
  int base = b * SCAN_CHUNK + t * 4;
  int v[4];
  int s = 0;
#pragma unroll
  for (int i = 0; i < 4; ++i) {
    int idx = base + i;
    v[i] = (idx < N_NODES) ? counts[idx] : 0;
    s += v[i];
  }
  sdata[t] = s;
  __syncthreads();
  for (int off = 1; off < 256; off <<= 1) {
    int x = (t >= off) ? sdata[t - off] : 0;
    __syncthreads();
    sdata[t] += x;
    __syncthreads();
  }
  int excl = (t == 0) ? 0 : sdata[t - 1];
  int o = blockSums[b] + excl;
#pragma unroll
  for (int i = 0; i < 4; ++i) {
    int idx = base + i;
    if (idx < N_NODES) rs[idx] = o;
    o += v[i];
  }
}

// non-atomic fill into interleaved meta {src, ew}
__global__ __launch_bounds__(256) void fill_kernel(
    const int* __restrict__ src, const int* __restrict__ dst,
    const float* __restrict__ ew, const int* __restrict__ rs,
    const int* __restrict__ p_local, uint2* __restrict__ meta) {
  int e = blockIdx.x * 256 + threadIdx.x;
  if (e < N_EDGES) {
    int d = dst[e];
    int pos = rs[d] + p_local[e];
    uint2 m;
    m.x = (unsigned)src[e];
    m.y = __float_as_uint(ew[e]);     // raw ew; normalized later
    meta[pos] = m;
  }
}

// deg from CSR (coalesced, no atomics) + fused dinv
__global__ __launch_bounds__(256) void degsum_kernel(
    const int* __restrict__ rs, const uint2* __restrict__ meta,
    float* __restrict__ dinv) {
  int n = blockIdx.x * 256 + threadIdx.x;
  if (n >= N_NODES) return;
  int b = rs[n], e = rs[n + 1];
  float s = 1.0f;              // self-loop weight
  for (int i = b; i < e; ++i) s += __uint_as_float(meta[i].y);
  dinv[n] = 1.0f / sqrtf(s);
}

// meta.y = dinv[src]*ew  (dst factor applied in spmm epilogue)
__global__ __launch_bounds__(256) void norm_kernel(
    uint2* __restrict__ meta, const float* __restrict__ dinv) {
  int e = blockIdx.x * 256 + threadIdx.x;
  if (e < N_EDGES) {
    uint2 m = meta[e];
    meta[e].y = __float_as_uint(__uint_as_float(m.y) * dinv[m.x]);
  }
}

// ---------------- input prep ----------------
// round emb_x to bf16, slice-major layout [NSL][N_PAD][32]
__global__ __launch_bounds__(256) void round_x_kernel(
    const float* __restrict__ x, ushort* __restrict__ tab, int n4) {
  int i = blockIdx.x * 256 + threadIdx.x;
  if (i >= n4) return;
  int n = i >> 6;              // node (64 quads per row)
  int q = i & 63;
  int s = q >> 3;              // slice
  int c = (q & 7) * 4;         // dim within slice
  float4 v = ((const float4*)x)[i];
  ushort4 h;
  h.x = bf16_hi(v.x);
  h.y = bf16_hi(v.y);
  h.z = bf16_hi(v.z);
  h.w = bf16_hi(v.w);
  *(ushort4*)(tab + ((size_t)s * N_PAD + n) * 32 + c) = h;
}

// zero pad rows [N_NODES, N_PAD) of the slice-major A table
__global__ __launch_bounds__(256) void pad0_kernel(ushort* __restrict__ tab) {
  int i = blockIdx.x * 256 + threadIdx.x;           // NSL*(N_PAD-N_NODES)*32
  int c = i & 31;
  int r = (i >> 5) % (N_PAD - N_NODES);
  int s = i / ((N_PAD - N_NODES) * 32);
  if (s < NSL) tab[((size_t)s * N_PAD + N_NODES + r) * 32 + c] = 0;
}

// transpose + split weights: W [K=256][N=256] f32 -> Wt_hi/Wt_lo [N][K] bf16
__global__ __launch_bounds__(256) void prep_w_kernel(
    const float* __restrict__ W1, const float* __restrict__ W2, const float* __restrict__ W3,
    ushort* __restrict__ wt) {
  int k = blockIdx.x;
  int w = blockIdx.y;
  int n = threadIdx.x;
  const float* W = (w == 0) ? W1 : (w == 1) ? W2 : W3;
  float v = W[k * 256 + n];
  ushort h, l;
  bf16_split(v, h, l);
  ushort* hplane = wt + (size_t)w * 2 * 256 * 256;
  ushort* lplane = hplane + 256 * 256;
  hplane[n * 256 + k] = h;
  lplane[n * 256 + k] = l;
}

// ---------------- bf16 MFMA GEMM: A (slice-major) in LDS dbuf, W from L2 ----
// XW = round_bf16( A @ (Wh+Wl) ); BM=64, BN=256, BK=32 (=1 slice), 4 waves.
#define GBM 64
#define GBK 32

__device__ __forceinline__ void gload16(const void* g, void* l) {
  __builtin_amdgcn_global_load_lds(
      (const __attribute__((address_space(1))) void*)g,
      (__attribute__((address_space(3))) void*)l, 16, 0, 0);
}

__global__ __launch_bounds__(256) void gemm_mfma(
    const ushort* __restrict__ A,                                  // [NSL][N_PAD][32]
    const ushort* __restrict__ Wh, const ushort* __restrict__ Wl,  // [256][256] n-major
    ushort* __restrict__ C, int M) {                               // [NSL][N_PAD][32]
  __shared__ ushort Asl[2][GBM * GBK];   // 2 x 4KB
  int tid = threadIdx.x;
  int bm = blockIdx.x * GBM;
  int wave = tid >> 6, lane = tid & 63;
  int wc = wave * 64;
  int l15 = lane & 15;
  int lkb = lane >> 4;

  f32x4 acc[4][4];
#pragma unroll
  for (int i = 0; i < 4; ++i)
#pragma unroll
    for (int j = 0; j < 4; ++j) acc[i][j] = (f32x4){0.f, 0.f, 0.f, 0.f};

  int arow = tid & 63, akb = tid >> 6;   // A slot = tid = akb*64 + arow

#define STAGE_A(buf, ts)                                                       \
  gload16(A + ((size_t)(ts) * N_PAD + bm + arow) * 32 + akb * 8,               \
          &Asl[buf][tid * 8])

  STAGE_A(0, 0);
  __syncthreads();
  int cur = 0;
  for (int t = 0; t < 8; ++t) {
    if (t < 7) STAGE_A(cur ^ 1, t + 1);   // prefetch next A k-step (= slice)
    s16x8 af[4], bh[4], bl[4];
#pragma unroll
    for (int f = 0; f < 4; ++f) {
      size_t woff = (size_t)(wc + f * 16 + l15) * 256 + t * 32 + lkb * 8;
      bh[f] = *(const s16x8*)(Wh + woff);
      bl[f] = *(const s16x8*)(Wl + woff);
    }
#pragma unroll
    for (int f = 0; f < 4; ++f)
      af[f] = *(const s16x8*)(&Asl[cur][(lkb * 64 + f * 16 + l15) * 8]);
#pragma unroll
    for (int i = 0; i < 4; ++i)
#pragma unroll
      for (int j = 0; j < 4; ++j) {
        acc[i][j] = __builtin_amdgcn_mfma_f32_16x16x32_bf16(af[i], bh[j], acc[i][j], 0, 0, 0);
        acc[i][j] = __builtin_amdgcn_mfma_f32_16x16x32_bf16(af[i], bl[j], acc[i][j], 0, 0, 0);
      }
    __syncthreads();
    cur ^= 1;
  }
#undef STAGE_A

#pragma unroll
  for (int i = 0; i < 4; ++i) {
    int rbase = bm + i * 16 + (lane >> 4) * 4;
#pragma unroll
    for (int j = 0; j < 4; ++j) {
      int col = wc + j * 16 + l15;
      size_t cbase = (size_t)(col >> 5) * N_PAD * 32 + (col & 31);
#pragma unroll
      for (int r = 0; r < 4; ++r) {
        int row = rbase + r;
        if (row < M) C[cbase + (size_t)row * 32] = bf16_hi(acc[i][j][r]);
      }
    }
  }
}

// ---------------- XCD-sliced SpMM v3: wave = 4 nodes x 4 edge-slots x 4 quads
// block = 4 waves = 16 nodes of one slice; slice = blockIdx&7 (round-robin->XCD,
// keeps each 3.2MB slice table resident in one XCD's L2).
// Lane walks every-4th edge of its node, loading its 16B quad of the 64B row.
// Reduce over edge-slots = shfl_xor(4) + shfl_xor(8).
// result = di * sum(w_norm * x_src) + di^2 * x_self + bias, relu.
// MODE 0: write bf16 slice-major table; MODE 1: write f32 row-major.
template <int MODE>
__global__ __launch_bounds__(256) void spmm_slice3(
    const ushort* __restrict__ tab, const int* __restrict__ rs,
    const uint2* __restrict__ meta, const float* __restrict__ dinv,
    const float* __restrict__ bias,
    float* __restrict__ xf32, ushort* __restrict__ xout) {
  int bid = blockIdx.x;
  int s = bid & 7;
  int nb = bid >> 3;
  int wave = threadIdx.x >> 6, lane = threadIdx.x & 63;
  int node_sub = lane >> 4;          // 0..3
  int eg = (lane >> 2) & 3;          // edge slot 0..3
  int q = lane & 3;                  // 16B quad 0..3
  int n = nb * 16 + wave * 4 + node_sub;   // 3125*16 = 50000 exact
  const ushort* base = tab + (size_t)s * N_PAD * 32 + q * 8;
  float acc[8] = {};
  int beg = rs[n], end = rs[n + 1];
  for (int i = beg + eg; i < end; i += 4) {
    uint2 m = meta[i];
    float w = __uint_as_float(m.y);
    s16x8 v = *(const s16x8*)(base + (size_t)m.x * 32);
#pragma unroll
    for (int j = 0; j < 8; ++j) acc[j] += w * bf16_up((ushort)v[j]);
  }
#pragma unroll
  for (int j = 0; j < 8; ++j) {
    acc[j] += __shfl_xor(acc[j], 4);
    acc[j] += __shfl_xor(acc[j], 8);
  }
  if (eg == 0) {
    float di = dinv[n];
    float dd = di * di;
    s16x8 sv = *(const s16x8*)(base + (size_t)n * 32);
    int d0 = s * 32 + q * 8;
    const float4* bb = (const float4*)(bias + d0);
    float4 b0 = bb[0], b1 = bb[1];
    float r[8];
#pragma unroll
    for (int j = 0; j < 8; ++j) r[j] = di * acc[j] + dd * bf16_up((ushort)sv[j]);
    r[0] = fmaxf(r[0] + b0.x, 0.f);
    r[1] = fmaxf(r[1] + b0.y, 0.f);
    r[2] = fmaxf(r[2] + b0.z, 0.f);
    r[3] = fmaxf(r[3] + b0.w, 0.f);
    r[4] = fmaxf(r[4] + b1.x, 0.f);
    r[5] = fmaxf(r[5] + b1.y, 0.f);
    r[6] = fmaxf(r[6] + b1.z, 0.f);
    r[7] = fmaxf(r[7] + b1.w, 0.f);
    if (MODE == 1) {
      float4 a0, a1;
      a0.x = r[0]; a0.y = r[1]; a0.z = r[2]; a0.w = r[3];
      a1.x = r[4]; a1.y = r[5]; a1.z = r[6]; a1.w = r[7];
      float* p = xf32 + (size_t)n * 256 + d0;
      *(float4*)p = a0;
      *(float4*)(p + 4) = a1;
    } else {
      s16x8 hv;
#pragma unroll
      for (int j = 0; j < 8; ++j) hv[j] = (short)bf16_hi(r[j]);
      *(s16x8*)(xout + ((size_t)s * N_PAD + n) * 32 + q * 8) = hv;
    }
  }
}

// ---------------- pooling ----------------
__device__ __forceinline__ int lower_bound_dev(const int* a, int n, int key) {
  int lo = 0, hi = n;
  while (lo < hi) {
    int mid = (lo + hi) >> 1;
    if (a[mid] < key) lo = mid + 1; else hi = mid;
  }
  return lo;
}

__global__ __launch_bounds__(256) void pool_kernel(
    const float* __restrict__ x, const int* __restrict__ batch,
    float* __restrict__ h) {
  int g = blockIdx.x;
  int dchunk = blockIdx.y;
  int t = threadIdx.x;
  int dl = t & 63;
  int nl = t >> 6;
  int d = dchunk * 64 + dl;
  int start = lower_bound_dev(batch, N_NODES, g);
  int end = lower_bound_dev(batch, N_NODES, g + 1);
  float sum = 0.f, mx = 0.f;
  for (int i = start + nl; i < end; i += 4) {
    float v = x[(size_t)i * DIM + d];
    sum += v;
    mx = fmaxf(mx, v);
  }
  __shared__ float ssum[4][64];
  __shared__ float smax[4][64];
  ssum[nl][dl] = sum;
  smax[nl][dl] = mx;
  __syncthreads();
  if (nl == 0) {
    sum = ssum[0][dl] + ssum[1][dl] + ssum[2][dl] + ssum[3][dl];
    mx = fmaxf(fmaxf(smax[0][dl], smax[1][dl]), fmaxf(smax[2][dl], smax[3][dl]));
    float cnt = (float)(end - start);
    h[(size_t)g * (2 * DIM) + d] = sum / fmaxf(cnt, 1.0f);
    h[(size_t)g * (2 * DIM) + DIM + d] = mx;
  }
}

// ---------------- FC head ----------------
__global__ __launch_bounds__(256) void fc_kernel(
    const float* __restrict__ h, const float* __restrict__ fc1_w,
    const float* __restrict__ fc1_b, const float* __restrict__ fc2_w,
    const float* __restrict__ fc2_b, float* __restrict__ out) {
  int g = blockIdx.x;
  int j = threadIdx.x;
  __shared__ float hs[2 * DIM];
  __shared__ float s0[256], s1[256];
  hs[j] = h[(size_t)g * (2 * DIM) + j];
  hs[j + 256] = h[(size_t)g * (2 * DIM) + 256 + j];
  __syncthreads();
  float acc = fc1_b[j];
  for (int k = 0; k < 2 * DIM; ++k) acc += hs[k] * fc1_w[(size_t)k * DIM + j];
  float r = fmaxf(acc, 0.0f);
  s0[j] = r * fc2_w[j * 2 + 0];
  s1[j] = r * fc2_w[j * 2 + 1];
  __syncthreads();
  for (int off = 128; off > 0; off >>= 1) {
    if (j < off) { s0[j] += s0[j + off]; s1[j] += s1[j + off]; }
    __syncthreads();
  }
  if (j == 0) {
    out[g * 2 + 0] = s0[0] + fc2_b[0];
    out[g * 2 + 1] = s1[0] + fc2_b[1];
  }
}

extern "C" void kernel_launch(void* const* d_in, const int* in_sizes, int n_in,
                              void* d_out, int out_size, void* d_ws, size_t ws_size,
                              hipStream_t stream) {
  const float* emb_x = (const float*)d_in[0];
  const int* eidx = (const int*)d_in[1];
  const int* esrc = eidx;
  const int* edst = eidx + N_EDGES;
  const float* ew = (const float*)d_in[2];
  const int* batch = (const int*)d_in[3];
  const float* W1 = (const float*)d_in[4];
  const float* b1 = (const float*)d_in[5];
  const float* W2 = (const float*)d_in[6];
  const float* b2 = (const float*)d_in[7];
  const float* W3 = (const float*)d_in[8];
  const float* b3 = (const float*)d_in[9];
  const float* fc1_w = (const float*)d_in[10];
  const float* fc1_b = (const float*)d_in[11];
  const float* fc2_w = (const float*)d_in[12];
  const float* fc2_b = (const float*)d_in[13];
  float* out = (float*)d_out;

  char* ws = (char*)d_ws;
  size_t off = 0;
  auto take = [&](size_t bytes) -> char* {
    char* p = ws + off;
    off = (off + bytes + 255) & ~(size_t)255;
    return p;
  };
  ushort* XW = (ushort*)take((size_t)NSL * N_PAD * 32 * 2);  // slice-major gather table
  ushort* Xa = (ushort*)take((size_t)NSL * N_PAD * 32 * 2);  // slice-major GEMM A
  float* Xf32 = (float*)take((size_t)N_NODES * DIM * 4);     // layer-3 f32 out for pooling
  ushort* WT = (ushort*)take((size_t)6 * 256 * 256 * 2);
  float* dinv = (float*)take(N_NODES * 4);
  int* counts = (int*)take(N_NODES * 4);
  int* rs = (int*)take((N_NODES + 1) * 4);
  int* p_local = (int*)take(N_EDGES * 4);
  int* blockSums = (int*)take(64 * 4);
  uint2* meta = (uint2*)take((size_t)N_EDGES * 8);
  float* h = (float*)take((size_t)N_GRAPHS * 2 * DIM * 4);

  hipMemsetAsync(counts, 0, N_NODES * 4, stream);

  int eblocks = (N_EDGES + 255) / 256;
  int nblocks = (N_NODES + 255) / 256;

  // CSR build
  count_kernel<<<eblocks, 256, 0, stream>>>(edst, counts, p_local);
  scan_phaseA<<<SCAN_BLOCKS, 256, 0, stream>>>(counts, blockSums);
  scan_phaseB<<<1, 64, 0, stream>>>(blockSums, rs);
  scan_phaseC<<<SCAN_BLOCKS, 256, 0, stream>>>(counts, blockSums, rs);
  fill_kernel<<<eblocks, 256, 0, stream>>>(esrc, edst, ew, rs, p_local, meta);
  degsum_kernel<<<nblocks, 256, 0, stream>>>(rs, meta, dinv);
  norm_kernel<<<eblocks, 256, 0, stream>>>(meta, dinv);

  // input prep
  round_x_kernel<<<(N_NODES * DIM / 4 + 255) / 256, 256, 0, stream>>>(
      emb_x, Xa, N_NODES * DIM / 4);
  pad0_kernel<<<(NSL * (N_PAD - N_NODES) * 32 + 255) / 256, 256, 0, stream>>>(Xa);
  prep_w_kernel<<<dim3(256, 3), 256, 0, stream>>>(W1, W2, W3, WT);

  ushort* W1h = WT + 0 * 65536; ushort* W1l = WT + 1 * 65536;
  ushort* W2h = WT + 2 * 65536; ushort* W2l = WT + 3 * 65536;
  ushort* W3h = WT + 4 * 65536; ushort* W3l = WT + 5 * 65536;

  dim3 ggrid(N_PAD / GBM);                 // 782 blocks
  int sgrid = (N_NODES / 16) * NSL;        // 25000 blocks

  // layer 1
  gemm_mfma<<<ggrid, 256, 0, stream>>>(Xa, W1h, W1l, XW, N_NODES);
  spmm_slice3<0><<<sgrid, 256, 0, stream>>>(XW, rs, meta, dinv, b1, nullptr, Xa);
  // layer 2
  gemm_mfma<<<ggrid, 256, 0, stream>>>(Xa, W2h, W2l, XW, N_NODES);
  spmm_slice3<0><<<sgrid, 256, 0, stream>>>(XW, rs, meta, dinv, b2, nullptr, Xa);
  // layer 3
  gemm_mfma<<<ggrid, 256, 0, stream>>>(Xa, W3h, W3l, XW, N_NODES);
  spmm_slice3<1><<<sgrid, 256, 0, stream>>>(XW, rs, meta, dinv, b3, Xf32, nullptr);

  pool_kernel<<<dim3(N_GRAPHS, 4), 256, 0, stream>>>(Xf32, batch, h);
  fc_kernel<<<N_GRAPHS, 256, 0, stream>>>(h, fc1_w, fc1_b, fc2_w, fc2_b, out);
}

// Round 10
// 452.121 us; speedup vs baseline: 1.0629x; 1.0629x over previous
//
#include <hip/hip_runtime.h>
#include <math.h>

#define N_NODES 50000
#define N_PAD 50048          // multiple of 64 above 50000
#define N_EDGES 800000
#define DIM 256
#define N_GRAPHS 128

using f32x4 = __attribute__((ext_vector_type(4))) float;
using s16x8 = __attribute__((ext_vector_type(8))) short;

// ---------------- bf16 helpers ----------------
__device__ __forceinline__ ushort bf16_hi(float f) {
  unsigned u = __float_as_uint(f);
  return (ushort)((u + 0x7FFFu + ((u >> 16) & 1u)) >> 16);
}
__device__ __forceinline__ float bf16_up(ushort h) {
  return __uint_as_float(((unsigned)h) << 16);
}
__device__ __forceinline__ void bf16_split(float f, ushort& hh, ushort& ll) {
  hh = bf16_hi(f);
  float d = f - bf16_up(hh);
  ll = bf16_hi(d);
}

// ---------------- CSR build (atomic count only) ----------------
__global__ __launch_bounds__(256) void count_kernel(
    const int* __restrict__ dst, int* __restrict__ counts,
    int* __restrict__ p_local) {
  int e = blockIdx.x * 256 + threadIdx.x;
  if (e < N_EDGES) p_local[e] = atomicAdd(&counts[dst[e]], 1);
}

#define SCAN_CHUNK 1024
#define SCAN_BLOCKS ((N_NODES + SCAN_CHUNK - 1) / SCAN_CHUNK)

__global__ __launch_bounds__(256) void scan_phaseA(
    const int* __restrict__ counts, int* __restrict__ blockSums) {
  __shared__ int sdata[256];
  int b = blockIdx.x, t = threadIdx.x;
  int base = b * SCAN_CHUNK + t * 4;
  int s = 0;
#pragma unroll
  for (int i = 0; i < 4; ++i) {
    int idx = base + i;
    if (idx < N_NODES) s += counts[idx];
  }
  sdata[t] = s;
  __syncthreads();
  for (int off = 128; off > 0; off >>= 1) {
    if (t < off) sdata[t] += sdata[t + off];
    __syncthreads();
  }
  if (t == 0) blockSums[b] = sdata[0];
}

__global__ void scan_phaseB(int* __restrict__ blockSums, int* __restrict__ rs) {
  if (threadIdx.x == 0 && blockIdx.x == 0) {
    int acc = 0;
    for (int i = 0; i < SCAN_BLOCKS; ++i) {
      int v = blockSums[i];
      blockSums[i] = acc;
      acc += v;
    }
    rs[N_NODES] = acc;
  }
}

__global__ __launch_bounds__(256) void scan_phaseC(
    const int* __restrict__ counts, const int* __restrict__ blockSums,
    int* __restrict__ rs) {
  __shared__ int sdata[256];
  int b = blockIdx.x, t = threadIdx.x;
  int base = b * SCAN_CHUNK + t * 4;
  int v[4];
  int s = 0;
#pragma unroll
  for (int i = 0; i < 4; ++i) {
    int idx = base + i;
    v[i] = (idx < N_NODES) ? counts[idx] : 0;
    s += v[i];
  }
  sdata[t] = s;
  __syncthreads();
  for (int off = 1; off < 256; off <<= 1) {
    int x = (t >= off) ? sdata[t - off] : 0;
    __syncthreads();
    sdata[t] += x;
    __syncthreads();
  }
  int excl = (t == 0) ? 0 : sdata[t - 1];
  int o = blockSums[b] + excl;
#pragma unroll
  for (int i = 0; i < 4; ++i) {
    int idx = base + i;
    if (idx < N_NODES) rs[idx] = o;
    o += v[i];
  }
}

// non-atomic fill: pos = rs[dst] + p_local
__global__ __launch_bounds__(256) void fill_kernel(
    const int* __restrict__ src, const int* __restrict__ dst,
    const float* __restrict__ ew, const int* __restrict__ rs,
    const int* __restrict__ p_local,
    int* __restrict__ csrc, float* __restrict__ cw) {
  int e = blockIdx.x * 256 + threadIdx.x;
  if (e < N_EDGES) {
    int d = dst[e];
    int pos = rs[d] + p_local[e];
    csrc[pos] = src[e];
    cw[pos] = ew[e];           // raw ew; normalized later
  }
}

// deg from CSR (coalesced, no atomics) + fused dinv
__global__ __launch_bounds__(256) void degsum_kernel(
    const int* __restrict__ rs, const float* __restrict__ cw,
    float* __restrict__ dinv) {
  int n = blockIdx.x * 256 + threadIdx.x;
  if (n >= N_NODES) return;
  int b = rs[n], e = rs[n + 1];
  float s = 1.0f;              // self-loop weight
  for (int i = b; i < e; ++i) s += cw[i];
  dinv[n] = 1.0f / sqrtf(s);
}

// cw[i] = dinv[src]*ew  (dst factor applied in spmm epilogue)
__global__ __launch_bounds__(256) void norm_kernel(
    const int* __restrict__ csrc, const float* __restrict__ dinv,
    float* __restrict__ cw) {
  int e = blockIdx.x * 256 + threadIdx.x;
  if (e < N_EDGES) cw[e] = cw[e] * dinv[csrc[e]];
}

// ---------------- input prep ----------------
// round emb_x to bf16, row-major [N_PAD][256]
__global__ __launch_bounds__(256) void round_x_kernel(
    const float* __restrict__ x, ushort* __restrict__ tab, int n4) {
  int i = blockIdx.x * 256 + threadIdx.x;
  if (i >= n4) return;
  float4 v = ((const float4*)x)[i];
  ushort4 h;
  h.x = bf16_hi(v.x);
  h.y = bf16_hi(v.y);
  h.z = bf16_hi(v.z);
  h.w = bf16_hi(v.w);
  ((ushort4*)tab)[i] = h;
}

// transpose + split weights: W [K=256][N=256] f32 -> Wt_hi/Wt_lo [N][K] bf16
__global__ __launch_bounds__(256) void prep_w_kernel(
    const float* __restrict__ W1, const float* __restrict__ W2, const float* __restrict__ W3,
    ushort* __restrict__ wt) {
  int k = blockIdx.x;
  int w = blockIdx.y;
  int n = threadIdx.x;
  const float* W = (w == 0) ? W1 : (w == 1) ? W2 : W3;
  float v = W[k * 256 + n];
  ushort h, l;
  bf16_split(v, h, l);
  ushort* hplane = wt + (size_t)w * 2 * 256 * 256;
  ushort* lplane = hplane + 256 * 256;
  hplane[n * 256 + k] = h;
  lplane[n * 256 + k] = l;
}

// ---------------- bf16 MFMA GEMM: A in LDS (8KB dbuf), W from L2 w/ reg dbuf -
// XW = round_bf16( A @ (Wh+Wl) ); BM=64, BN=256, BK=32, 4 waves.
// W fragments for step t+1 are prefetched into registers while step t's MFMA
// runs; A is global_load_lds double-buffered. Full unroll -> static indexing.
#define GBM 64
#define GBK 32

__device__ __forceinline__ void gload16(const void* g, void* l) {
  __builtin_amdgcn_global_load_lds(
      (const __attribute__((address_space(1))) void*)g,
      (__attribute__((address_space(3))) void*)l, 16, 0, 0);
}

__global__ __launch_bounds__(256) void gemm_mfma(
    const ushort* __restrict__ A,                                  // [N_PAD][256] bf16
    const ushort* __restrict__ Wh, const ushort* __restrict__ Wl,  // [256][256] n-major
    ushort* __restrict__ C, int M) {                               // [N_PAD][256] bf16
  __shared__ ushort Asl[2][GBM * GBK];   // 2 x 4KB
  int tid = threadIdx.x;
  int bm = blockIdx.x * GBM;
  int wave = tid >> 6, lane = tid & 63;
  int wc = wave * 64;
  int l15 = lane & 15;
  int lkb = lane >> 4;

  f32x4 acc[4][4];
#pragma unroll
  for (int i = 0; i < 4; ++i)
#pragma unroll
    for (int j = 0; j < 4; ++j) acc[i][j] = (f32x4){0.f, 0.f, 0.f, 0.f};

  int arow = tid & 63, akb = tid >> 6;   // A slot = tid = akb*64 + arow

#define STAGE_A(buf, ts)                                                       \
  gload16(A + (size_t)(bm + arow) * 256 + (ts) * 32 + akb * 8,                 \
          &Asl[buf][tid * 8])

  STAGE_A(0, 0);
  // preload W fragments for t=0
  s16x8 bh_c[4], bl_c[4], bh_n[4], bl_n[4];
#pragma unroll
  for (int f = 0; f < 4; ++f) {
    size_t woff = (size_t)(wc + f * 16 + l15) * 256 + lkb * 8;
    bh_c[f] = *(const s16x8*)(Wh + woff);
    bl_c[f] = *(const s16x8*)(Wl + woff);
  }
  __syncthreads();
#pragma unroll
  for (int t = 0; t < 8; ++t) {
    if (t < 7) {
      STAGE_A((t & 1) ^ 1, t + 1);   // prefetch next A k-step into other buf
#pragma unroll
      for (int f = 0; f < 4; ++f) {  // prefetch next W frags into regs
        size_t woff = (size_t)(wc + f * 16 + l15) * 256 + (t + 1) * 32 + lkb * 8;
        bh_n[f] = *(const s16x8*)(Wh + woff);
        bl_n[f] = *(const s16x8*)(Wl + woff);
      }
    }
    s16x8 af[4];
#pragma unroll
    for (int f = 0; f < 4; ++f)
      af[f] = *(const s16x8*)(&Asl[t & 1][(lkb * 64 + f * 16 + l15) * 8]);
#pragma unroll
    for (int i = 0; i < 4; ++i)
#pragma unroll
      for (int j = 0; j < 4; ++j) {
        acc[i][j] = __builtin_amdgcn_mfma_f32_16x16x32_bf16(af[i], bh_c[j], acc[i][j], 0, 0, 0);
        acc[i][j] = __builtin_amdgcn_mfma_f32_16x16x32_bf16(af[i], bl_c[j], acc[i][j], 0, 0, 0);
      }
    __syncthreads();
#pragma unroll
    for (int f = 0; f < 4; ++f) { bh_c[f] = bh_n[f]; bl_c[f] = bl_n[f]; }
  }
#undef STAGE_A

#pragma unroll
  for (int i = 0; i < 4; ++i) {
    int rbase = bm + i * 16 + (lane >> 4) * 4;
#pragma unroll
    for (int j = 0; j < 4; ++j) {
      int col = wc + j * 16 + l15;
#pragma unroll
      for (int r = 0; r < 4; ++r) {
        int row = rbase + r;
        if (row < M) C[(size_t)row * 256 + col] = bf16_hi(acc[i][j][r]);
      }
    }
  }
}

// ---------------- SpMM v4: wave = node, 2 edges/iter x 16B lanes -------------
// lane = (e2 = lane>>5, c = lane&31): lane loads the 16B chunk c of edge
// (i + e2)'s source row. 8 edges per unrolled iter = 4 pair-steps.
// Halves gather request count vs 8B lanes (same bytes).
// Reduce over e2: one shfl_xor(32). result = di*sum + di^2*self + bias, relu.
// MODE 0: write bf16 row-major table; MODE 1: write f32 row-major.
template <int MODE>
__global__ __launch_bounds__(256) void spmm_row16(
    const ushort* __restrict__ xw, const int* __restrict__ rs,
    const int* __restrict__ csrc, const float* __restrict__ cw,
    const float* __restrict__ dinv, const float* __restrict__ bias,
    float* __restrict__ xf32, ushort* __restrict__ xout) {
  int wave = threadIdx.x >> 6, lane = threadIdx.x & 63;
  int n = __builtin_amdgcn_readfirstlane(blockIdx.x * 4 + wave);  // 50000=12500*4
  int e2 = lane >> 5;                // which edge of the pair
  int c = lane & 31;                 // 16B chunk (8 bf16 dims)
  const ushort* chunk = xw + c * 8;  // + idx*256
  float acc[8] = {};
  int beg = __builtin_amdgcn_readfirstlane(rs[n]);
  int end = __builtin_amdgcn_readfirstlane(rs[n + 1]);
  int i = beg;
  for (; i + 8 <= end; i += 8) {
    int idx[4];
    float w[4];
    s16x8 v[4];
#pragma unroll
    for (int u = 0; u < 4; ++u) {
      idx[u] = csrc[i + 2 * u + e2];
      w[u] = cw[i + 2 * u + e2];
    }
#pragma unroll
    for (int u = 0; u < 4; ++u) v[u] = *(const s16x8*)(chunk + (size_t)idx[u] * 256);
#pragma unroll
    for (int u = 0; u < 4; ++u)
#pragma unroll
      for (int j = 0; j < 8; ++j) acc[j] += w[u] * bf16_up((ushort)v[u][j]);
  }
  for (; i < end; i += 2) {
    int ii = i + e2;
    float w = (ii < end) ? cw[ii] : 0.f;
    int id = csrc[(ii < end) ? ii : (end - 1)];
    s16x8 v = *(const s16x8*)(chunk + (size_t)id * 256);
#pragma unroll
    for (int j = 0; j < 8; ++j) acc[j] += w * bf16_up((ushort)v[j]);
  }
#pragma unroll
  for (int j = 0; j < 8; ++j) acc[j] += __shfl_xor(acc[j], 32);
  if (e2 == 0) {
    float di = dinv[n];
    float dd = di * di;
    s16x8 sv = *(const s16x8*)(chunk + (size_t)n * 256);
    int d0 = c * 8;
    const float4* bb = (const float4*)(bias + d0);
    float4 b0 = bb[0], b1 = bb[1];
    float r[8];
#pragma unroll
    for (int j = 0; j < 8; ++j) r[j] = di * acc[j] + dd * bf16_up((ushort)sv[j]);
    r[0] = fmaxf(r[0] + b0.x, 0.f);
    r[1] = fmaxf(r[1] + b0.y, 0.f);
    r[2] = fmaxf(r[2] + b0.z, 0.f);
    r[3] = fmaxf(r[3] + b0.w, 0.f);
    r[4] = fmaxf(r[4] + b1.x, 0.f);
    r[5] = fmaxf(r[5] + b1.y, 0.f);
    r[6] = fmaxf(r[6] + b1.z, 0.f);
    r[7] = fmaxf(r[7] + b1.w, 0.f);
    if (MODE == 1) {
      float4 a0, a1;
      a0.x = r[0]; a0.y = r[1]; a0.z = r[2]; a0.w = r[3];
      a1.x = r[4]; a1.y = r[5]; a1.z = r[6]; a1.w = r[7];
      float* p = xf32 + (size_t)n * 256 + d0;
      *(float4*)p = a0;
      *(float4*)(p + 4) = a1;
    } else {
      s16x8 hv;
#pragma unroll
      for (int j = 0; j < 8; ++j) hv[j] = (short)bf16_hi(r[j]);
      *(s16x8*)(xout + (size_t)n * 256 + d0) = hv;
    }
  }
}

// ---------------- pooling ----------------
__device__ __forceinline__ int lower_bound_dev(const int* a, int n, int key) {
  int lo = 0, hi = n;
  while (lo < hi) {
    int mid = (lo + hi) >> 1;
    if (a[mid] < key) lo = mid + 1; else hi = mid;
  }
  return lo;
}

__global__ __launch_bounds__(256) void pool_kernel(
    const float* __restrict__ x, const int* __restrict__ batch,
    float* __restrict__ h) {
  int g = blockIdx.x;
  int dchunk = blockIdx.y;
  int t = threadIdx.x;
  int dl = t & 63;
  int nl = t >> 6;
  int d = dchunk * 64 + dl;
  int start = lower_bound_dev(batch, N_NODES, g);
  int end = lower_bound_dev(batch, N_NODES, g + 1);
  float sum = 0.f, mx = 0.f;
  for (int i = start + nl; i < end; i += 4) {
    float v = x[(size_t)i * DIM + d];
    sum += v;
    mx = fmaxf(mx, v);
  }
  __shared__ float ssum[4][64];
  __shared__ float smax[4][64];
  ssum[nl][dl] = sum;
  smax[nl][dl] = mx;
  __syncthreads();
  if (nl == 0) {
    sum = ssum[0][dl] + ssum[1][dl] + ssum[2][dl] + ssum[3][dl];
    mx = fmaxf(fmaxf(smax[0][dl], smax[1][dl]), fmaxf(smax[2][dl], smax[3][dl]));
    float cnt = (float)(end - start);
    h[(size_t)g * (2 * DIM) + d] = sum / fmaxf(cnt, 1.0f);
    h[(size_t)g * (2 * DIM) + DIM + d] = mx;
  }
}

// ---------------- FC head ----------------
__global__ __launch_bounds__(256) void fc_kernel(
    const float* __restrict__ h, const float* __restrict__ fc1_w,
    const float* __restrict__ fc1_b, const float* __restrict__ fc2_w,
    const float* __restrict__ fc2_b, float* __restrict__ out) {
  int g = blockIdx.x;
  int j = threadIdx.x;
  __shared__ float hs[2 * DIM];
  __shared__ float s0[256], s1[256];
  hs[j] = h[(size_t)g * (2 * DIM) + j];
  hs[j + 256] = h[(size_t)g * (2 * DIM) + 256 + j];
  __syncthreads();
  float acc = fc1_b[j];
  for (int k = 0; k < 2 * DIM; ++k) acc += hs[k] * fc1_w[(size_t)k * DIM + j];
  float r = fmaxf(acc, 0.0f);
  s0[j] = r * fc2_w[j * 2 + 0];
  s1[j] = r * fc2_w[j * 2 + 1];
  __syncthreads();
  for (int off = 128; off > 0; off >>= 1) {
    if (j < off) { s0[j] += s0[j + off]; s1[j] += s1[j + off]; }
    __syncthreads();
  }
  if (j == 0) {
    out[g * 2 + 0] = s0[0] + fc2_b[0];
    out[g * 2 + 1] = s1[0] + fc2_b[1];
  }
}

extern "C" void kernel_launch(void* const* d_in, const int* in_sizes, int n_in,
                              void* d_out, int out_size, void* d_ws, size_t ws_size,
                              hipStream_t stream) {
  const float* emb_x = (const float*)d_in[0];
  const int* eidx = (const int*)d_in[1];
  const int* esrc = eidx;
  const int* edst = eidx + N_EDGES;
  const float* ew = (const float*)d_in[2];
  const int* batch = (const int*)d_in[3];
  const float* W1 = (const float*)d_in[4];
  const float* b1 = (const float*)d_in[5];
  const float* W2 = (const float*)d_in[6];
  const float* b2 = (const float*)d_in[7];
  const float* W3 = (const float*)d_in[8];
  const float* b3 = (const float*)d_in[9];
  const float* fc1_w = (const float*)d_in[10];
  const float* fc1_b = (const float*)d_in[11];
  const float* fc2_w = (const float*)d_in[12];
  const float* fc2_b = (const float*)d_in[13];
  float* out = (float*)d_out;

  char* ws = (char*)d_ws;
  size_t off = 0;
  auto take = [&](size_t bytes) -> char* {
    char* p = ws + off;
    off = (off + bytes + 255) & ~(size_t)255;
    return p;
  };
  ushort* XW = (ushort*)take((size_t)N_PAD * DIM * 2);    // bf16 gather table
  ushort* Xa = (ushort*)take((size_t)N_PAD * DIM * 2);    // bf16 GEMM A
  float* Xf32 = (float*)take((size_t)N_NODES * DIM * 4);  // layer-3 f32 out for pooling
  ushort* WT = (ushort*)take((size_t)6 * 256 * 256 * 2);
  float* dinv = (float*)take(N_NODES * 4);
  int* counts = (int*)take(N_NODES * 4);
  int* rs = (int*)take((N_NODES + 1) * 4);
  int* p_local = (int*)take(N_EDGES * 4);
  int* blockSums = (int*)take(64 * 4);
  int* csrc = (int*)take(N_EDGES * 4);
  float* cw = (float*)take(N_EDGES * 4);
  float* h = (float*)take((size_t)N_GRAPHS * 2 * DIM * 4);

  hipMemsetAsync(counts, 0, N_NODES * 4, stream);
  // zero padded tail rows of Xa (read by gemm as A rows >= N_NODES)
  hipMemsetAsync(Xa + (size_t)N_NODES * DIM, 0, (size_t)(N_PAD - N_NODES) * DIM * 2, stream);

  int eblocks = (N_EDGES + 255) / 256;
  int nblocks = (N_NODES + 255) / 256;

  // CSR build
  count_kernel<<<eblocks, 256, 0, stream>>>(edst, counts, p_local);
  scan_phaseA<<<SCAN_BLOCKS, 256, 0, stream>>>(counts, blockSums);
  scan_phaseB<<<1, 64, 0, stream>>>(blockSums, rs);
  scan_phaseC<<<SCAN_BLOCKS, 256, 0, stream>>>(counts, blockSums, rs);
  fill_kernel<<<eblocks, 256, 0, stream>>>(esrc, edst, ew, rs, p_local, csrc, cw);
  degsum_kernel<<<nblocks, 256, 0, stream>>>(rs, cw, dinv);
  norm_kernel<<<eblocks, 256, 0, stream>>>(csrc, dinv, cw);

  // input prep
  round_x_kernel<<<(N_NODES * DIM / 4 + 255) / 256, 256, 0, stream>>>(
      emb_x, Xa, N_NODES * DIM / 4);
  prep_w_kernel<<<dim3(256, 3), 256, 0, stream>>>(W1, W2, W3, WT);

  ushort* W1h = WT + 0 * 65536; ushort* W1l = WT + 1 * 65536;
  ushort* W2h = WT + 2 * 65536; ushort* W2l = WT + 3 * 65536;
  ushort* W3h = WT + 4 * 65536; ushort* W3l = WT + 5 * 65536;

  dim3 ggrid(N_PAD / GBM);           // 782 blocks
  int sgrid = N_NODES / 4;           // 12500 blocks

  // layer 1
  gemm_mfma<<<ggrid, 256, 0, stream>>>(Xa, W1h, W1l, XW, N_NODES);
  spmm_row16<0><<<sgrid, 256, 0, stream>>>(XW, rs, csrc, cw, dinv, b1, nullptr, Xa);
  // layer 2
  gemm_mfma<<<ggrid, 256, 0, stream>>>(Xa, W2h, W2l, XW, N_NODES);
  spmm_row16<0><<<sgrid, 256, 0, stream>>>(XW, rs, csrc, cw, dinv, b2, nullptr, Xa);
  // layer 3
  gemm_mfma<<<ggrid, 256, 0, stream>>>(Xa, W3h, W3l, XW, N_NODES);
  spmm_row16<1><<<sgrid, 256, 0, stream>>>(XW, rs, csrc, cw, dinv, b3, Xf32, nullptr);

  pool_kernel<<<dim3(N_GRAPHS, 4), 256, 0, stream>>>(Xf32, batch, h);
  fc_kernel<<<N_GRAPHS, 256, 0, stream>>>(h, fc1_w, fc1_b, fc2_w, fc2_b, out);
}

// Round 11
// 448.903 us; speedup vs baseline: 1.0705x; 1.0072x over previous
//
#include <hip/hip_runtime.h>
#include <math.h>

#define N_NODES 50000
#define N_PAD 50048          // multiple of 64 above 50000
#define N_EDGES 800000
#define DIM 256
#define N_GRAPHS 128
#define NPART 8              // count partitions (~XCDs via round-robin dispatch)

using f32x4 = __attribute__((ext_vector_type(4))) float;
using s16x8 = __attribute__((ext_vector_type(8))) short;

// ---------------- bf16 helpers ----------------
__device__ __forceinline__ ushort bf16_hi(float f) {
  unsigned u = __float_as_uint(f);
  return (ushort)((u + 0x7FFFu + ((u >> 16) & 1u)) >> 16);
}
__device__ __forceinline__ float bf16_up(ushort h) {
  return __uint_as_float(((unsigned)h) << 16);
}
__device__ __forceinline__ void bf16_split(float f, ushort& hh, ushort& ll) {
  hh = bf16_hi(f);
  float d = f - bf16_up(hh);
  ll = bf16_hi(d);
}

// ---------------- CSR build: partitioned count (atomics stay XCD-local) -----
__global__ __launch_bounds__(256) void count8_kernel(
    const int* __restrict__ dst, int* __restrict__ counts8,
    int* __restrict__ p8) {
  int e = blockIdx.x * 256 + threadIdx.x;
  int part = blockIdx.x & (NPART - 1);
  if (e < N_EDGES) p8[e] = atomicAdd(&counts8[part * N_NODES + dst[e]], 1);
}

__global__ __launch_bounds__(256) void sum8_kernel(
    const int* __restrict__ counts8, int* __restrict__ counts) {
  int n = blockIdx.x * 256 + threadIdx.x;
  if (n < N_NODES) {
    int s = 0;
#pragma unroll
    for (int p = 0; p < NPART; ++p) s += counts8[p * N_NODES + n];
    counts[n] = s;
  }
}

#define SCAN_CHUNK 1024
#define SCAN_BLOCKS ((N_NODES + SCAN_CHUNK - 1) / SCAN_CHUNK)

__global__ __launch_bounds__(256) void scan_phaseA(
    const int* __restrict__ counts, int* __restrict__ blockSums) {
  __shared__ int sdata[256];
  int b = blockIdx.x, t = threadIdx.x;
  int base = b * SCAN_CHUNK + t * 4;
  int s = 0;
#pragma unroll
  for (int i = 0; i < 4; ++i) {
    int idx = base + i;
    if (idx < N_NODES) s += counts[idx];
  }
  sdata[t] = s;
  __syncthreads();
  for (int off = 128; off > 0; off >>= 1) {
    if (t < off) sdata[t] += sdata[t + off];
    __syncthreads();
  }
  if (t == 0) blockSums[b] = sdata[0];
}

__global__ void scan_phaseB(int* __restrict__ blockSums, int* __restrict__ rs) {
  if (threadIdx.x == 0 && blockIdx.x == 0) {
    int acc = 0;
    for (int i = 0; i < SCAN_BLOCKS; ++i) {
      int v = blockSums[i];
      blockSums[i] = acc;
      acc += v;
    }
    rs[N_NODES] = acc;
  }
}

__global__ __launch_bounds__(256) void scan_phaseC(
    const int* __restrict__ counts, const int* __restrict__ blockSums,
    int* __restrict__ rs) {
  __shared__ int sdata[256];
  int b = blockIdx.x, t = threadIdx.x;
  int base = b * SCAN_CHUNK + t * 4;
  int v[4];
  int s = 0;
#pragma unroll
  for (int i = 0; i < 4; ++i) {
    int idx = base + i;
    v[i] = (idx < N_NODES) ? counts[idx] : 0;
    s += v[i];
  }
  sdata[t] = s;
  __syncthreads();
  for (int off = 1; off < 256; off <<= 1) {
    int x = (t >= off) ? sdata[t - off] : 0;
    __syncthreads();
    sdata[t] += x;
    __syncthreads();
  }
  int excl = (t == 0) ? 0 : sdata[t - 1];
  int o = blockSums[b] + excl;
#pragma unroll
  for (int i = 0; i < 4; ++i) {
    int idx = base + i;
    if (idx < N_NODES) rs[idx] = o;
    o += v[i];
  }
}

// per-node, per-partition base offsets: off8[p][n] = rs[n] + sum_{p'<p} counts8[p'][n]
__global__ __launch_bounds__(256) void off8_kernel(
    const int* __restrict__ rs, const int* __restrict__ counts8,
    int* __restrict__ off8) {
  int n = blockIdx.x * 256 + threadIdx.x;
  if (n < N_NODES) {
    int acc = rs[n];
#pragma unroll
    for (int p = 0; p < NPART; ++p) {
      off8[p * N_NODES + n] = acc;
      acc += counts8[p * N_NODES + n];
    }
  }
}

// non-atomic fill into interleaved meta {src, ew}; partition must match count8
__global__ __launch_bounds__(256) void fill_kernel(
    const int* __restrict__ src, const int* __restrict__ dst,
    const float* __restrict__ ew, const int* __restrict__ off8,
    const int* __restrict__ p8, uint2* __restrict__ meta) {
  int e = blockIdx.x * 256 + threadIdx.x;
  int part = blockIdx.x & (NPART - 1);
  if (e < N_EDGES) {
    int d = dst[e];
    int pos = off8[part * N_NODES + d] + p8[e];
    uint2 m;
    m.x = (unsigned)src[e];
    m.y = __float_as_uint(ew[e]);     // raw ew; normalized later
    meta[pos] = m;
  }
}

// deg from CSR (coalesced, no atomics) + fused dinv
__global__ __launch_bounds__(256) void degsum_kernel(
    const int* __restrict__ rs, const uint2* __restrict__ meta,
    float* __restrict__ dinv) {
  int n = blockIdx.x * 256 + threadIdx.x;
  if (n >= N_NODES) return;
  int b = rs[n], e = rs[n + 1];
  float s = 1.0f;              // self-loop weight
  for (int i = b; i < e; ++i) s += __uint_as_float(meta[i].y);
  dinv[n] = 1.0f / sqrtf(s);
}

// meta.y = dinv[src]*ew  (dst factor applied in spmm epilogue)
__global__ __launch_bounds__(256) void norm_kernel(
    uint2* __restrict__ meta, const float* __restrict__ dinv) {
  int e = blockIdx.x * 256 + threadIdx.x;
  if (e < N_EDGES) {
    uint2 m = meta[e];
    meta[e].y = __float_as_uint(__uint_as_float(m.y) * dinv[m.x]);
  }
}

// ---------------- input prep ----------------
// round emb_x to bf16, row-major [N_PAD][256]
__global__ __launch_bounds__(256) void round_x_kernel(
    const float* __restrict__ x, ushort* __restrict__ tab, int n4) {
  int i = blockIdx.x * 256 + threadIdx.x;
  if (i >= n4) return;
  float4 v = ((const float4*)x)[i];
  ushort4 h;
  h.x = bf16_hi(v.x);
  h.y = bf16_hi(v.y);
  h.z = bf16_hi(v.z);
  h.w = bf16_hi(v.w);
  ((ushort4*)tab)[i] = h;
}

// transpose + split weights: W [K=256][N=256] f32 -> Wt_hi/Wt_lo [N][K] bf16
__global__ __launch_bounds__(256) void prep_w_kernel(
    const float* __restrict__ W1, const float* __restrict__ W2, const float* __restrict__ W3,
    ushort* __restrict__ wt) {
  int k = blockIdx.x;
  int w = blockIdx.y;
  int n = threadIdx.x;
  const float* W = (w == 0) ? W1 : (w == 1) ? W2 : W3;
  float v = W[k * 256 + n];
  ushort h, l;
  bf16_split(v, h, l);
  ushort* hplane = wt + (size_t)w * 2 * 256 * 256;
  ushort* lplane = hplane + 256 * 256;
  hplane[n * 256 + k] = h;
  lplane[n * 256 + k] = l;
}

// ---------------- barrier-free bf16 MFMA GEMM -------------------------------
// XW = round_bf16( A @ (Wh+Wl) ); BM=64, BN=256, 4 waves, K=256 (x2 planes).
// Whole 32KB A-tile staged to LDS ONCE (global_load_lds), ONE barrier, then
// 8 fully-unrolled k-steps with no further syncs (LDS is read-only after).
// W fragments register-double-buffered straight from L2 (256KB, all-block hot).
#define GBM 64

__device__ __forceinline__ void gload16(const void* g, void* l) {
  __builtin_amdgcn_global_load_lds(
      (const __attribute__((address_space(1))) void*)g,
      (__attribute__((address_space(3))) void*)l, 16, 0, 0);
}

__global__ __launch_bounds__(256) void gemm_mfma(
    const ushort* __restrict__ A,                                  // [N_PAD][256] bf16
    const ushort* __restrict__ Wh, const ushort* __restrict__ Wl,  // [256][256] n-major
    ushort* __restrict__ C, int M) {                               // [N_PAD][256] bf16
  __shared__ ushort Asl[GBM * 256];      // 32 KB; slot = (t*4+kb)*64+row, 16B each
  int tid = threadIdx.x;
  int bm = blockIdx.x * GBM;
  int wave = tid >> 6, lane = tid & 63;
  int wc = wave * 64;
  int l15 = lane & 15;
  int lkb = lane >> 4;

  f32x4 acc[4][4];
#pragma unroll
  for (int i = 0; i < 4; ++i)
#pragma unroll
    for (int j = 0; j < 4; ++j) acc[i][j] = (f32x4){0.f, 0.f, 0.f, 0.f};

  // stage ALL of A once: 2048 slots x 16B, 8 per thread
  int arow = tid & 63, akb = tid >> 6;
#pragma unroll
  for (int it = 0; it < 8; ++it) {
    gload16(A + (size_t)(bm + arow) * 256 + it * 32 + akb * 8,
            Asl + ((it * 256 + tid) * 8));
  }

  // preload W fragments for t=0 (independent of LDS)
  s16x8 bh_c[4], bl_c[4], bh_n[4], bl_n[4];
#pragma unroll
  for (int f = 0; f < 4; ++f) {
    size_t woff = (size_t)(wc + f * 16 + l15) * 256 + lkb * 8;
    bh_c[f] = *(const s16x8*)(Wh + woff);
    bl_c[f] = *(const s16x8*)(Wl + woff);
  }
  __syncthreads();   // compiler drains vmcnt here; LDS read-only afterwards

#pragma unroll
  for (int t = 0; t < 8; ++t) {
    if (t < 7) {
#pragma unroll
      for (int f = 0; f < 4; ++f) {  // prefetch next W frags into regs
        size_t woff = (size_t)(wc + f * 16 + l15) * 256 + (t + 1) * 32 + lkb * 8;
        bh_n[f] = *(const s16x8*)(Wh + woff);
        bl_n[f] = *(const s16x8*)(Wl + woff);
      }
    }
    s16x8 af[4];
#pragma unroll
    for (int f = 0; f < 4; ++f)
      af[f] = *(const s16x8*)(&Asl[(t * 256 + lkb * 64 + f * 16 + l15) * 8]);
#pragma unroll
    for (int i = 0; i < 4; ++i)
#pragma unroll
      for (int j = 0; j < 4; ++j) {
        acc[i][j] = __builtin_amdgcn_mfma_f32_16x16x32_bf16(af[i], bh_c[j], acc[i][j], 0, 0, 0);
        acc[i][j] = __builtin_amdgcn_mfma_f32_16x16x32_bf16(af[i], bl_c[j], acc[i][j], 0, 0, 0);
      }
    if (t < 7) {
#pragma unroll
      for (int f = 0; f < 4; ++f) { bh_c[f] = bh_n[f]; bl_c[f] = bl_n[f]; }
    }
  }

#pragma unroll
  for (int i = 0; i < 4; ++i) {
    int rbase = bm + i * 16 + (lane >> 4) * 4;
#pragma unroll
    for (int j = 0; j < 4; ++j) {
      int col = wc + j * 16 + l15;
#pragma unroll
      for (int r = 0; r < 4; ++r) {
        int row = rbase + r;
        if (row < M) C[(size_t)row * 256 + col] = bf16_hi(acc[i][j][r]);
      }
    }
  }
}

// ---------------- SpMM: wave = node, 2 edges/iter x 16B lanes, meta uint2 ----
// lane = (e2 = lane>>5, c = lane&31). Reduce over e2: one shfl_xor(32).
// result = di*sum(w_norm*x_src) + di^2*x_self + bias, relu.
// MODE 0: write bf16 row-major table; MODE 1: write f32 row-major.
template <int MODE>
__global__ __launch_bounds__(256) void spmm_row16(
    const ushort* __restrict__ xw, const int* __restrict__ rs,
    const uint2* __restrict__ meta, const float* __restrict__ dinv,
    const float* __restrict__ bias,
    float* __restrict__ xf32, ushort* __restrict__ xout) {
  int wave = threadIdx.x >> 6, lane = threadIdx.x & 63;
  int n = __builtin_amdgcn_readfirstlane(blockIdx.x * 4 + wave);  // 50000=12500*4
  int e2 = lane >> 5;                // which edge of the pair
  int c = lane & 31;                 // 16B chunk (8 bf16 dims)
  const ushort* chunk = xw + c * 8;  // + idx*256
  float acc[8] = {};
  int beg = __builtin_amdgcn_readfirstlane(rs[n]);
  int end = __builtin_amdgcn_readfirstlane(rs[n + 1]);
  int i = beg;
  for (; i + 8 <= end; i += 8) {
    uint2 m[4];
    s16x8 v[4];
#pragma unroll
    for (int u = 0; u < 4; ++u) m[u] = meta[i + 2 * u + e2];
#pragma unroll
    for (int u = 0; u < 4; ++u) v[u] = *(const s16x8*)(chunk + (size_t)m[u].x * 256);
#pragma unroll
    for (int u = 0; u < 4; ++u) {
      float w = __uint_as_float(m[u].y);
#pragma unroll
      for (int j = 0; j < 8; ++j) acc[j] += w * bf16_up((ushort)v[u][j]);
    }
  }
  for (; i < end; i += 2) {
    int ii = i + e2;
    uint2 m = meta[(ii < end) ? ii : (end - 1)];
    float w = (ii < end) ? __uint_as_float(m.y) : 0.f;
    s16x8 v = *(const s16x8*)(chunk + (size_t)m.x * 256);
#pragma unroll
    for (int j = 0; j < 8; ++j) acc[j] += w * bf16_up((ushort)v[j]);
  }
#pragma unroll
  for (int j = 0; j < 8; ++j) acc[j] += __shfl_xor(acc[j], 32);
  if (e2 == 0) {
    float di = dinv[n];
    float dd = di * di;
    s16x8 sv = *(const s16x8*)(chunk + (size_t)n * 256);
    int d0 = c * 8;
    const float4* bb = (const float4*)(bias + d0);
    float4 b0 = bb[0], b1 = bb[1];
    float r[8];
#pragma unroll
    for (int j = 0; j < 8; ++j) r[j] = di * acc[j] + dd * bf16_up((ushort)sv[j]);
    r[0] = fmaxf(r[0] + b0.x, 0.f);
    r[1] = fmaxf(r[1] + b0.y, 0.f);
    r[2] = fmaxf(r[2] + b0.z, 0.f);
    r[3] = fmaxf(r[3] + b0.w, 0.f);
    r[4] = fmaxf(r[4] + b1.x, 0.f);
    r[5] = fmaxf(r[5] + b1.y, 0.f);
    r[6] = fmaxf(r[6] + b1.z, 0.f);
    r[7] = fmaxf(r[7] + b1.w, 0.f);
    if (MODE == 1) {
      float4 a0, a1;
      a0.x = r[0]; a0.y = r[1]; a0.z = r[2]; a0.w = r[3];
      a1.x = r[4]; a1.y = r[5]; a1.z = r[6]; a1.w = r[7];
      float* p = xf32 + (size_t)n * 256 + d0;
      *(float4*)p = a0;
      *(float4*)(p + 4) = a1;
    } else {
      s16x8 hv;
#pragma unroll
      for (int j = 0; j < 8; ++j) hv[j] = (short)bf16_hi(r[j]);
      *(s16x8*)(xout + (size_t)n * 256 + d0) = hv;
    }
  }
}

// ---------------- pooling ----------------
__device__ __forceinline__ int lower_bound_dev(const int* a, int n, int key) {
  int lo = 0, hi = n;
  while (lo < hi) {
    int mid = (lo + hi) >> 1;
    if (a[mid] < key) lo = mid + 1; else hi = mid;
  }
  return lo;
}

__global__ __launch_bounds__(256) void pool_kernel(
    const float* __restrict__ x, const int* __restrict__ batch,
    float* __restrict__ h) {
  int g = blockIdx.x;
  int dchunk = blockIdx.y;
  int t = threadIdx.x;
  int dl = t & 63;
  int nl = t >> 6;
  int d = dchunk * 64 + dl;
  int start = lower_bound_dev(batch, N_NODES, g);
  int end = lower_bound_dev(batch, N_NODES, g + 1);
  float sum = 0.f, mx = 0.f;
  for (int i = start + nl; i < end; i += 4) {
    float v = x[(size_t)i * DIM + d];
    sum += v;
    mx = fmaxf(mx, v);
  }
  __shared__ float ssum[4][64];
  __shared__ float smax[4][64];
  ssum[nl][dl] = sum;
  smax[nl][dl] = mx;
  __syncthreads();
  if (nl == 0) {
    sum = ssum[0][dl] + ssum[1][dl] + ssum[2][dl] + ssum[3][dl];
    mx = fmaxf(fmaxf(smax[0][dl], smax[1][dl]), fmaxf(smax[2][dl], smax[3][dl]));
    float cnt = (float)(end - start);
    h[(size_t)g * (2 * DIM) + d] = sum / fmaxf(cnt, 1.0f);
    h[(size_t)g * (2 * DIM) + DIM + d] = mx;
  }
}

// ---------------- FC head ----------------
__global__ __launch_bounds__(256) void fc_kernel(
    const float* __restrict__ h, const float* __restrict__ fc1_w,
    const float* __restrict__ fc1_b, const float* __restrict__ fc2_w,
    const float* __restrict__ fc2_b, float* __restrict__ out) {
  int g = blockIdx.x;
  int j = threadIdx.x;
  __shared__ float hs[2 * DIM];
  __shared__ float s0[256], s1[256];
  hs[j] = h[(size_t)g * (2 * DIM) + j];
  hs[j + 256] = h[(size_t)g * (2 * DIM) + 256 + j];
  __syncthreads();
  float acc = fc1_b[j];
  for (int k = 0; k < 2 * DIM; ++k) acc += hs[k] * fc1_w[(size_t)k * DIM + j];
  float r = fmaxf(acc, 0.0f);
  s0[j] = r * fc2_w[j * 2 + 0];
  s1[j] = r * fc2_w[j * 2 + 1];
  __syncthreads();
  for (int off = 128; off > 0; off >>= 1) {
    if (j < off) { s0[j] += s0[j + off]; s1[j] += s1[j + off]; }
    __syncthreads();
  }
  if (j == 0) {
    out[g * 2 + 0] = s0[0] + fc2_b[0];
    out[g * 2 + 1] = s1[0] + fc2_b[1];
  }
}

extern "C" void kernel_launch(void* const* d_in, const int* in_sizes, int n_in,
                              void* d_out, int out_size, void* d_ws, size_t ws_size,
                              hipStream_t stream) {
  const float* emb_x = (const float*)d_in[0];
  const int* eidx = (const int*)d_in[1];
  const int* esrc = eidx;
  const int* edst = eidx + N_EDGES;
  const float* ew = (const float*)d_in[2];
  const int* batch = (const int*)d_in[3];
  const float* W1 = (const float*)d_in[4];
  const float* b1 = (const float*)d_in[5];
  const float* W2 = (const float*)d_in[6];
  const float* b2 = (const float*)d_in[7];
  const float* W3 = (const float*)d_in[8];
  const float* b3 = (const float*)d_in[9];
  const float* fc1_w = (const float*)d_in[10];
  const float* fc1_b = (const float*)d_in[11];
  const float* fc2_w = (const float*)d_in[12];
  const float* fc2_b = (const float*)d_in[13];
  float* out = (float*)d_out;

  char* ws = (char*)d_ws;
  size_t off = 0;
  auto take = [&](size_t bytes) -> char* {
    char* p = ws + off;
    off = (off + bytes + 255) & ~(size_t)255;
    return p;
  };
  ushort* XW = (ushort*)take((size_t)N_PAD * DIM * 2);    // bf16 gather table
  ushort* Xa = (ushort*)take((size_t)N_PAD * DIM * 2);    // bf16 GEMM A
  float* Xf32 = (float*)take((size_t)N_NODES * DIM * 4);  // layer-3 f32 out for pooling
  ushort* WT = (ushort*)take((size_t)6 * 256 * 256 * 2);
  float* dinv = (float*)take(N_NODES * 4);
  int* counts = (int*)take(N_NODES * 4);
  int* counts8 = (int*)take((size_t)NPART * N_NODES * 4);
  int* off8 = (int*)take((size_t)NPART * N_NODES * 4);
  int* rs = (int*)take((N_NODES + 1) * 4);
  int* p8 = (int*)take(N_EDGES * 4);
  int* blockSums = (int*)take(64 * 4);
  uint2* meta = (uint2*)take((size_t)N_EDGES * 8);
  float* h = (float*)take((size_t)N_GRAPHS * 2 * DIM * 4);

  hipMemsetAsync(counts8, 0, (size_t)NPART * N_NODES * 4, stream);
  // zero padded tail rows of Xa (read by gemm as A rows >= N_NODES)
  hipMemsetAsync(Xa + (size_t)N_NODES * DIM, 0, (size_t)(N_PAD - N_NODES) * DIM * 2, stream);

  int eblocks = (N_EDGES + 255) / 256;
  int nblocks = (N_NODES + 255) / 256;

  // CSR build
  count8_kernel<<<eblocks, 256, 0, stream>>>(edst, counts8, p8);
  sum8_kernel<<<nblocks, 256, 0, stream>>>(counts8, counts);
  scan_phaseA<<<SCAN_BLOCKS, 256, 0, stream>>>(counts, blockSums);
  scan_phaseB<<<1, 64, 0, stream>>>(blockSums, rs);
  scan_phaseC<<<SCAN_BLOCKS, 256, 0, stream>>>(counts, blockSums, rs);
  off8_kernel<<<nblocks, 256, 0, stream>>>(rs, counts8, off8);
  fill_kernel<<<eblocks, 256, 0, stream>>>(esrc, edst, ew, off8, p8, meta);
  degsum_kernel<<<nblocks, 256, 0, stream>>>(rs, meta, dinv);
  norm_kernel<<<eblocks, 256, 0, stream>>>(meta, dinv);

  // input prep
  round_x_kernel<<<(N_NODES * DIM / 4 + 255) / 256, 256, 0, stream>>>(
      emb_x, Xa, N_NODES * DIM / 4);
  prep_w_kernel<<<dim3(256, 3), 256, 0, stream>>>(W1, W2, W3, WT);

  ushort* W1h = WT + 0 * 65536; ushort* W1l = WT + 1 * 65536;
  ushort* W2h = WT + 2 * 65536; ushort* W2l = WT + 3 * 65536;
  ushort* W3h = WT + 4 * 65536; ushort* W3l = WT + 5 * 65536;

  dim3 ggrid(N_PAD / GBM);           // 782 blocks
  int sgrid = N_NODES / 4;           // 12500 blocks

  // layer 1
  gemm_mfma<<<ggrid, 256, 0, stream>>>(Xa, W1h, W1l, XW, N_NODES);
  spmm_row16<0><<<sgrid, 256, 0, stream>>>(XW, rs, meta, dinv, b1, nullptr, Xa);
  // layer 2
  gemm_mfma<<<ggrid, 256, 0, stream>>>(Xa, W2h, W2l, XW, N_NODES);
  spmm_row16<0><<<sgrid, 256, 0, stream>>>(XW, rs, meta, dinv, b2, nullptr, Xa);
  // layer 3
  gemm_mfma<<<ggrid, 256, 0, stream>>>(Xa, W3h, W3l, XW, N_NODES);
  spmm_row16<1><<<sgrid, 256, 0, stream>>>(XW, rs, meta, dinv, b3, Xf32, nullptr);

  pool_kernel<<<dim3(N_GRAPHS, 4), 256, 0, stream>>>(Xf32, batch, h);
  fc_kernel<<<N_GRAPHS, 256, 0, stream>>>(h, fc1_w, fc1_b, fc2_w, fc2_b, out);
}

// Round 12
// 440.868 us; speedup vs baseline: 1.0900x; 1.0182x over previous
//
#include <hip/hip_runtime.h>
#include <math.h>

#define N_NODES 50000
#define N_PAD 50048          // multiple of 64 above 50000
#define N_EDGES 800000
#define DIM 256
#define N_GRAPHS 128
#define NPART 8              // count partitions (~XCDs via round-robin dispatch)

using f32x4 = __attribute__((ext_vector_type(4))) float;
using s16x8 = __attribute__((ext_vector_type(8))) short;

// ---------------- bf16 helpers ----------------
__device__ __forceinline__ ushort bf16_hi(float f) {
  unsigned u = __float_as_uint(f);
  return (ushort)((u + 0x7FFFu + ((u >> 16) & 1u)) >> 16);
}
__device__ __forceinline__ float bf16_up(ushort h) {
  return __uint_as_float(((unsigned)h) << 16);
}
__device__ __forceinline__ void bf16_split(float f, ushort& hh, ushort& ll) {
  hh = bf16_hi(f);
  float d = f - bf16_up(hh);
  ll = bf16_hi(d);
}

// ---------------- CSR build: partitioned count (atomics stay XCD-local) -----
__global__ __launch_bounds__(256) void count8_kernel(
    const int* __restrict__ dst, int* __restrict__ counts8,
    int* __restrict__ p8) {
  int e = blockIdx.x * 256 + threadIdx.x;
  int part = blockIdx.x & (NPART - 1);
  if (e < N_EDGES) p8[e] = atomicAdd(&counts8[part * N_NODES + dst[e]], 1);
}

#define SCAN_CHUNK 1024
#define SCAN_BLOCKS ((N_NODES + SCAN_CHUNK - 1) / SCAN_CHUNK)

// fused sum8 + scan phase A: counts[n] = sum_p counts8[p][n]; blockSums = chunk totals
__global__ __launch_bounds__(256) void scan_phaseA(
    const int* __restrict__ counts8, int* __restrict__ counts,
    int* __restrict__ blockSums) {
  __shared__ int sdata[256];
  int b = blockIdx.x, t = threadIdx.x;
  int base = b * SCAN_CHUNK + t * 4;
  int s = 0;
#pragma unroll
  for (int i = 0; i < 4; ++i) {
    int idx = base + i;
    if (idx < N_NODES) {
      int c = 0;
#pragma unroll
      for (int p = 0; p < NPART; ++p) c += counts8[p * N_NODES + idx];
      counts[idx] = c;
      s += c;
    }
  }
  sdata[t] = s;
  __syncthreads();
  for (int off = 128; off > 0; off >>= 1) {
    if (t < off) sdata[t] += sdata[t + off];
    __syncthreads();
  }
  if (t == 0) blockSums[b] = sdata[0];
}

__global__ void scan_phaseB(int* __restrict__ blockSums, int* __restrict__ rs) {
  if (threadIdx.x == 0 && blockIdx.x == 0) {
    int acc = 0;
    for (int i = 0; i < SCAN_BLOCKS; ++i) {
      int v = blockSums[i];
      blockSums[i] = acc;
      acc += v;
    }
    rs[N_NODES] = acc;
  }
}

// fused scan phase C + off8: rs[n] and per-partition bases off8[p][n]
__global__ __launch_bounds__(256) void scan_phaseC(
    const int* __restrict__ counts, const int* __restrict__ counts8,
    const int* __restrict__ blockSums, int* __restrict__ rs,
    int* __restrict__ off8) {
  __shared__ int sdata[256];
  int b = blockIdx.x, t = threadIdx.x;
  int base = b * SCAN_CHUNK + t * 4;
  int v[4];
  int s = 0;
#pragma unroll
  for (int i = 0; i < 4; ++i) {
    int idx = base + i;
    v[i] = (idx < N_NODES) ? counts[idx] : 0;
    s += v[i];
  }
  sdata[t] = s;
  __syncthreads();
  for (int off = 1; off < 256; off <<= 1) {
    int x = (t >= off) ? sdata[t - off] : 0;
    __syncthreads();
    sdata[t] += x;
    __syncthreads();
  }
  int excl = (t == 0) ? 0 : sdata[t - 1];
  int o = blockSums[b] + excl;
#pragma unroll
  for (int i = 0; i < 4; ++i) {
    int idx = base + i;
    if (idx < N_NODES) {
      rs[idx] = o;
      int acc = o;
#pragma unroll
      for (int p = 0; p < NPART; ++p) {
        off8[p * N_NODES + idx] = acc;
        acc += counts8[p * N_NODES + idx];
      }
    }
    o += v[i];
  }
}

// non-atomic fill into interleaved meta {src, ew}; partition must match count8
__global__ __launch_bounds__(256) void fill_kernel(
    const int* __restrict__ src, const int* __restrict__ dst,
    const float* __restrict__ ew, const int* __restrict__ off8,
    const int* __restrict__ p8, uint2* __restrict__ meta) {
  int e = blockIdx.x * 256 + threadIdx.x;
  int part = blockIdx.x & (NPART - 1);
  if (e < N_EDGES) {
    int d = dst[e];
    int pos = off8[part * N_NODES + d] + p8[e];
    uint2 m;
    m.x = (unsigned)src[e];
    m.y = __float_as_uint(ew[e]);     // raw ew; normalized later
    meta[pos] = m;
  }
}

// deg from CSR (coalesced, no atomics) + fused dinv
__global__ __launch_bounds__(256) void degsum_kernel(
    const int* __restrict__ rs, const uint2* __restrict__ meta,
    float* __restrict__ dinv) {
  int n = blockIdx.x * 256 + threadIdx.x;
  if (n >= N_NODES) return;
  int b = rs[n], e = rs[n + 1];
  float s = 1.0f;              // self-loop weight
  for (int i = b; i < e; ++i) s += __uint_as_float(meta[i].y);
  dinv[n] = 1.0f / sqrtf(s);
}

// meta.y = dinv[src]*ew  (dst factor applied in spmm epilogue)
__global__ __launch_bounds__(256) void norm_kernel(
    uint2* __restrict__ meta, const float* __restrict__ dinv) {
  int e = blockIdx.x * 256 + threadIdx.x;
  if (e < N_EDGES) {
    uint2 m = meta[e];
    meta[e].y = __float_as_uint(__uint_as_float(m.y) * dinv[m.x]);
  }
}

// ---------------- fused input prep ----------------
// blocks [0, 12512): round emb_x to bf16 row-major [N_PAD][256], zeroing pad rows
// blocks [12512, 12512+768): transpose+split W1..W3 -> Wt hi/lo [N][K] bf16
#define PREP_X_BLOCKS (N_PAD * (DIM / 4) / 256)   // 12512

__global__ __launch_bounds__(256) void prep_all(
    const float* __restrict__ x, ushort* __restrict__ tab,
    const float* __restrict__ W1, const float* __restrict__ W2,
    const float* __restrict__ W3, ushort* __restrict__ wt) {
  int b = blockIdx.x;
  int t = threadIdx.x;
  if (b < PREP_X_BLOCKS) {
    int i = b * 256 + t;           // quad index over N_PAD*64
    int n = i >> 6;
    ushort4 h = {0, 0, 0, 0};
    if (n < N_NODES) {
      float4 v = ((const float4*)x)[i];
      h.x = bf16_hi(v.x);
      h.y = bf16_hi(v.y);
      h.z = bf16_hi(v.z);
      h.w = bf16_hi(v.w);
    }
    ((ushort4*)tab)[i] = h;
  } else {
    int bb = b - PREP_X_BLOCKS;    // 0..767
    int k = bb & 255;
    int w = bb >> 8;
    const float* W = (w == 0) ? W1 : (w == 1) ? W2 : W3;
    float v = W[k * 256 + t];
    ushort h, l;
    bf16_split(v, h, l);
    ushort* hplane = wt + (size_t)w * 2 * 256 * 256;
    ushort* lplane = hplane + 256 * 256;
    hplane[t * 256 + k] = h;
    lplane[t * 256 + k] = l;
  }
}

// ---------------- barrier-free bf16 MFMA GEMM -------------------------------
// XW = round_bf16( A @ (Wh+Wl) ); BM=64, BN=256, 4 waves, K=256 (x2 planes).
// Whole 32KB A-tile staged to LDS ONCE (global_load_lds), ONE barrier, then
// 8 fully-unrolled k-steps with no further syncs (LDS is read-only after).
// W fragments register-double-buffered straight from L2 (256KB, all-block hot).
#define GBM 64

__device__ __forceinline__ void gload16(const void* g, void* l) {
  __builtin_amdgcn_global_load_lds(
      (const __attribute__((address_space(1))) void*)g,
      (__attribute__((address_space(3))) void*)l, 16, 0, 0);
}

__global__ __launch_bounds__(256) void gemm_mfma(
    const ushort* __restrict__ A,                                  // [N_PAD][256] bf16
    const ushort* __restrict__ Wh, const ushort* __restrict__ Wl,  // [256][256] n-major
    ushort* __restrict__ C, int M) {                               // [N_PAD][256] bf16
  __shared__ ushort Asl[GBM * 256];      // 32 KB; slot = (t*4+kb)*64+row, 16B each
  int tid = threadIdx.x;
  int bm = blockIdx.x * GBM;
  int wave = tid >> 6, lane = tid & 63;
  int wc = wave * 64;
  int l15 = lane & 15;
  int lkb = lane >> 4;

  f32x4 acc[4][4];
#pragma unroll
  for (int i = 0; i < 4; ++i)
#pragma unroll
    for (int j = 0; j < 4; ++j) acc[i][j] = (f32x4){0.f, 0.f, 0.f, 0.f};

  // stage ALL of A once: 2048 slots x 16B, 8 per thread
  int arow = tid & 63, akb = tid >> 6;
#pragma unroll
  for (int it = 0; it < 8; ++it) {
    gload16(A + (size_t)(bm + arow) * 256 + it * 32 + akb * 8,
            Asl + ((it * 256 + tid) * 8));
  }

  // preload W fragments for t=0 (independent of LDS)
  s16x8 bh_c[4], bl_c[4], bh_n[4], bl_n[4];
#pragma unroll
  for (int f = 0; f < 4; ++f) {
    size_t woff = (size_t)(wc + f * 16 + l15) * 256 + lkb * 8;
    bh_c[f] = *(const s16x8*)(Wh + woff);
    bl_c[f] = *(const s16x8*)(Wl + woff);
  }
  __syncthreads();   // compiler drains vmcnt here; LDS read-only afterwards

#pragma unroll
  for (int t = 0; t < 8; ++t) {
    if (t < 7) {
#pragma unroll
      for (int f = 0; f < 4; ++f) {  // prefetch next W frags into regs
        size_t woff = (size_t)(wc + f * 16 + l15) * 256 + (t + 1) * 32 + lkb * 8;
        bh_n[f] = *(const s16x8*)(Wh + woff);
        bl_n[f] = *(const s16x8*)(Wl + woff);
      }
    }
    s16x8 af[4];
#pragma unroll
    for (int f = 0; f < 4; ++f)
      af[f] = *(const s16x8*)(&Asl[(t * 256 + lkb * 64 + f * 16 + l15) * 8]);
#pragma unroll
    for (int i = 0; i < 4; ++i)
#pragma unroll
      for (int j = 0; j < 4; ++j) {
        acc[i][j] = __builtin_amdgcn_mfma_f32_16x16x32_bf16(af[i], bh_c[j], acc[i][j], 0, 0, 0);
        acc[i][j] = __builtin_amdgcn_mfma_f32_16x16x32_bf16(af[i], bl_c[j], acc[i][j], 0, 0, 0);
      }
    if (t < 7) {
#pragma unroll
      for (int f = 0; f < 4; ++f) { bh_c[f] = bh_n[f]; bl_c[f] = bl_n[f]; }
    }
  }

#pragma unroll
  for (int i = 0; i < 4; ++i) {
    int rbase = bm + i * 16 + (lane >> 4) * 4;
#pragma unroll
    for (int j = 0; j < 4; ++j) {
      int col = wc + j * 16 + l15;
#pragma unroll
      for (int r = 0; r < 4; ++r) {
        int row = rbase + r;
        if (row < M) C[(size_t)row * 256 + col] = bf16_hi(acc[i][j][r]);
      }
    }
  }
}

// ---------------- SpMM: wave = node, 2 edges/iter x 16B lanes, meta uint2 ----
// lane = (e2 = lane>>5, c = lane&31). Reduce over e2: one shfl_xor(32).
// result = di*sum(w_norm*x_src) + di^2*x_self + bias, relu.
// MODE 0: write bf16 row-major table; MODE 1: write f32 row-major.
template <int MODE>
__global__ __launch_bounds__(256) void spmm_row16(
    const ushort* __restrict__ xw, const int* __restrict__ rs,
    const uint2* __restrict__ meta, const float* __restrict__ dinv,
    const float* __restrict__ bias,
    float* __restrict__ xf32, ushort* __restrict__ xout) {
  int wave = threadIdx.x >> 6, lane = threadIdx.x & 63;
  int n = __builtin_amdgcn_readfirstlane(blockIdx.x * 4 + wave);  // 50000=12500*4
  int e2 = lane >> 5;                // which edge of the pair
  int c = lane & 31;                 // 16B chunk (8 bf16 dims)
  const ushort* chunk = xw + c * 8;  // + idx*256
  float acc[8] = {};
  int beg = __builtin_amdgcn_readfirstlane(rs[n]);
  int end = __builtin_amdgcn_readfirstlane(rs[n + 1]);
  int i = beg;
  for (; i + 8 <= end; i += 8) {
    uint2 m[4];
    s16x8 v[4];
#pragma unroll
    for (int u = 0; u < 4; ++u) m[u] = meta[i + 2 * u + e2];
#pragma unroll
    for (int u = 0; u < 4; ++u) v[u] = *(const s16x8*)(chunk + (size_t)m[u].x * 256);
#pragma unroll
    for (int u = 0; u < 4; ++u) {
      float w = __uint_as_float(m[u].y);
#pragma unroll
      for (int j = 0; j < 8; ++j) acc[j] += w * bf16_up((ushort)v[u][j]);
    }
  }
  for (; i < end; i += 2) {
    int ii = i + e2;
    uint2 m = meta[(ii < end) ? ii : (end - 1)];
    float w = (ii < end) ? __uint_as_float(m.y) : 0.f;
    s16x8 v = *(const s16x8*)(chunk + (size_t)m.x * 256);
#pragma unroll
    for (int j = 0; j < 8; ++j) acc[j] += w * bf16_up((ushort)v[j]);
  }
#pragma unroll
  for (int j = 0; j < 8; ++j) acc[j] += __shfl_xor(acc[j], 32);
  if (e2 == 0) {
    float di = dinv[n];
    float dd = di * di;
    s16x8 sv = *(const s16x8*)(chunk + (size_t)n * 256);
    int d0 = c * 8;
    const float4* bb = (const float4*)(bias + d0);
    float4 b0 = bb[0], b1 = bb[1];
    float r[8];
#pragma unroll
    for (int j = 0; j < 8; ++j) r[j] = di * acc[j] + dd * bf16_up((ushort)sv[j]);
    r[0] = fmaxf(r[0] + b0.x, 0.f);
    r[1] = fmaxf(r[1] + b0.y, 0.f);
    r[2] = fmaxf(r[2] + b0.z, 0.f);
    r[3] = fmaxf(r[3] + b0.w, 0.f);
    r[4] = fmaxf(r[4] + b1.x, 0.f);
    r[5] = fmaxf(r[5] + b1.y, 0.f);
    r[6] = fmaxf(r[6] + b1.z, 0.f);
    r[7] = fmaxf(r[7] + b1.w, 0.f);
    if (MODE == 1) {
      float4 a0, a1;
      a0.x = r[0]; a0.y = r[1]; a0.z = r[2]; a0.w = r[3];
      a1.x = r[4]; a1.y = r[5]; a1.z = r[6]; a1.w = r[7];
      float* p = xf32 + (size_t)n * 256 + d0;
      *(float4*)p = a0;
      *(float4*)(p + 4) = a1;
    } else {
      s16x8 hv;
#pragma unroll
      for (int j = 0; j < 8; ++j) hv[j] = (short)bf16_hi(r[j]);
      *(s16x8*)(xout + (size_t)n * 256 + d0) = hv;
    }
  }
}

// ---------------- pooling ----------------
__device__ __forceinline__ int lower_bound_dev(const int* a, int n, int key) {
  int lo = 0, hi = n;
  while (lo < hi) {
    int mid = (lo + hi) >> 1;
    if (a[mid] < key) lo = mid + 1; else hi = mid;
  }
  return lo;
}

__global__ __launch_bounds__(256) void pool_kernel(
    const float* __restrict__ x, const int* __restrict__ batch,
    float* __restrict__ h) {
  int g = blockIdx.x;
  int dchunk = blockIdx.y;
  int t = threadIdx.x;
  int dl = t & 63;
  int nl = t >> 6;
  int d = dchunk * 64 + dl;
  int start = lower_bound_dev(batch, N_NODES, g);
  int end = lower_bound_dev(batch, N_NODES, g + 1);
  float sum = 0.f, mx = 0.f;
  for (int i = start + nl; i < end; i += 4) {
    float v = x[(size_t)i * DIM + d];
    sum += v;
    mx = fmaxf(mx, v);
  }
  __shared__ float ssum[4][64];
  __shared__ float smax[4][64];
  ssum[nl][dl] = sum;
  smax[nl][dl] = mx;
  __syncthreads();
  if (nl == 0) {
    sum = ssum[0][dl] + ssum[1][dl] + ssum[2][dl] + ssum[3][dl];
    mx = fmaxf(fmaxf(smax[0][dl], smax[1][dl]), fmaxf(smax[2][dl], smax[3][dl]));
    float cnt = (float)(end - start);
    h[(size_t)g * (2 * DIM) + d] = sum / fmaxf(cnt, 1.0f);
    h[(size_t)g * (2 * DIM) + DIM + d] = mx;
  }
}

// ---------------- FC head ----------------
__global__ __launch_bounds__(256) void fc_kernel(
    const float* __restrict__ h, const float* __restrict__ fc1_w,
    const float* __restrict__ fc1_b, const float* __restrict__ fc2_w,
    const float* __restrict__ fc2_b, float* __restrict__ out) {
  int g = blockIdx.x;
  int j = threadIdx.x;
  __shared__ float hs[2 * DIM];
  __shared__ float s0[256], s1[256];
  hs[j] = h[(size_t)g * (2 * DIM) + j];
  hs[j + 256] = h[(size_t)g * (2 * DIM) + 256 + j];
  __syncthreads();
  float acc = fc1_b[j];
  for (int k = 0; k < 2 * DIM; ++k) acc += hs[k] * fc1_w[(size_t)k * DIM + j];
  float r = fmaxf(acc, 0.0f);
  s0[j] = r * fc2_w[j * 2 + 0];
  s1[j] = r * fc2_w[j * 2 + 1];
  __syncthreads();
  for (int off = 128; off > 0; off >>= 1) {
    if (j < off) { s0[j] += s0[j + off]; s1[j] += s1[j + off]; }
    __syncthreads();
  }
  if (j == 0) {
    out[g * 2 + 0] = s0[0] + fc2_b[0];
    out[g * 2 + 1] = s1[0] + fc2_b[1];
  }
}

extern "C" void kernel_launch(void* const* d_in, const int* in_sizes, int n_in,
                              void* d_out, int out_size, void* d_ws, size_t ws_size,
                              hipStream_t stream) {
  const float* emb_x = (const float*)d_in[0];
  const int* eidx = (const int*)d_in[1];
  const int* esrc = eidx;
  const int* edst = eidx + N_EDGES;
  const float* ew = (const float*)d_in[2];
  const int* batch = (const int*)d_in[3];
  const float* W1 = (const float*)d_in[4];
  const float* b1 = (const float*)d_in[5];
  const float* W2 = (const float*)d_in[6];
  const float* b2 = (const float*)d_in[7];
  const float* W3 = (const float*)d_in[8];
  const float* b3 = (const float*)d_in[9];
  const float* fc1_w = (const float*)d_in[10];
  const float* fc1_b = (const float*)d_in[11];
  const float* fc2_w = (const float*)d_in[12];
  const float* fc2_b = (const float*)d_in[13];
  float* out = (float*)d_out;

  char* ws = (char*)d_ws;
  size_t off = 0;
  auto take = [&](size_t bytes) -> char* {
    char* p = ws + off;
    off = (off + bytes + 255) & ~(size_t)255;
    return p;
  };
  ushort* XW = (ushort*)take((size_t)N_PAD * DIM * 2);    // bf16 gather table
  ushort* Xa = (ushort*)take((size_t)N_PAD * DIM * 2);    // bf16 GEMM A
  float* Xf32 = (float*)take((size_t)N_NODES * DIM * 4);  // layer-3 f32 out for pooling
  ushort* WT = (ushort*)take((size_t)6 * 256 * 256 * 2);
  float* dinv = (float*)take(N_NODES * 4);
  int* counts = (int*)take(N_NODES * 4);
  int* counts8 = (int*)take((size_t)NPART * N_NODES * 4);
  int* off8 = (int*)take((size_t)NPART * N_NODES * 4);
  int* rs = (int*)take((N_NODES + 1) * 4);
  int* p8 = (int*)take(N_EDGES * 4);
  int* blockSums = (int*)take(64 * 4);
  uint2* meta = (uint2*)take((size_t)N_EDGES * 8);
  float* h = (float*)take((size_t)N_GRAPHS * 2 * DIM * 4);

  hipMemsetAsync(counts8, 0, (size_t)NPART * N_NODES * 4, stream);

  int eblocks = (N_EDGES + 255) / 256;
  int nblocks = (N_NODES + 255) / 256;

  // CSR build (fused: sum8 in scanA, off8 in scanC)
  count8_kernel<<<eblocks, 256, 0, stream>>>(edst, counts8, p8);
  scan_phaseA<<<SCAN_BLOCKS, 256, 0, stream>>>(counts8, counts, blockSums);
  scan_phaseB<<<1, 64, 0, stream>>>(blockSums, rs);
  scan_phaseC<<<SCAN_BLOCKS, 256, 0, stream>>>(counts, counts8, blockSums, rs, off8);
  fill_kernel<<<eblocks, 256, 0, stream>>>(esrc, edst, ew, off8, p8, meta);
  degsum_kernel<<<nblocks, 256, 0, stream>>>(rs, meta, dinv);
  norm_kernel<<<eblocks, 256, 0, stream>>>(meta, dinv);

  // fused input prep (round_x incl. pad zeros + prep_w)
  prep_all<<<PREP_X_BLOCKS + 768, 256, 0, stream>>>(emb_x, Xa, W1, W2, W3, WT);

  ushort* W1h = WT + 0 * 65536; ushort* W1l = WT + 1 * 65536;
  ushort* W2h = WT + 2 * 65536; ushort* W2l = WT + 3 * 65536;
  ushort* W3h = WT + 4 * 65536; ushort* W3l = WT + 5 * 65536;

  dim3 ggrid(N_PAD / GBM);           // 782 blocks
  int sgrid = N_NODES / 4;           // 12500 blocks

  // layer 1
  gemm_mfma<<<ggrid, 256, 0, stream>>>(Xa, W1h, W1l, XW, N_NODES);
  spmm_row16<0><<<sgrid, 256, 0, stream>>>(XW, rs, meta, dinv, b1, nullptr, Xa);
  // layer 2
  gemm_mfma<<<ggrid, 256, 0, stream>>>(Xa, W2h, W2l, XW, N_NODES);
  spmm_row16<0><<<sgrid, 256, 0, stream>>>(XW, rs, meta, dinv, b2, nullptr, Xa);
  // layer 3
  gemm_mfma<<<ggrid, 256, 0, stream>>>(Xa, W3h, W3l, XW, N_NODES);
  spmm_row16<1><<<sgrid, 256, 0, stream>>>(XW, rs, meta, dinv, b3, Xf32, nullptr);

  pool_kernel<<<dim3(N_GRAPHS, 4), 256, 0, stream>>>(Xf32, batch, h);
  fc_kernel<<<N_GRAPHS, 256, 0, stream>>>(h, fc1_w, fc1_b, fc2_w, fc2_b, out);
}